// Round 11
// baseline (16923.665 us; speedup 1.0000x reference)
//
#include <hip/hip_runtime.h>

#define NBATCH 64
#define NSEQ   32
#define NI     31
#define NC     16
#define NH     128
#define NW     256
#define NOUT   10
#define NSUB   62          // 31 intervals * 2 substeps

#define NGRP 8             // batch groups == XCDs (real XCC_ID grouping)
#define GB   8             // batch rows per group
#define NSL  32            // slice blocks per group == CUs per XCD
#define NBLK (NGRP*NSL)    // 256 blocks = 1 per CU (LDS-forced)
#define BS   512

// per-slice weight ownership
#define L1R 8              // fw0 rows  (256/32)
#define L2R 8              // fw1 rows  (256/32)
#define L3H 4              // h-dims of fw2 (128/32)
#define L3R 64             // fw2 rows = L3H*16

// padded LDS strides (floats)
#define P128 132
#define P256 260

// workspace layout (bytes)
#define WS_BAR   0                       // 8 groups * 32 slots * 64B = 16 KB
#define WS_CTRL  16384                   // 8 u64 rank counters
#define WS_H1    (16384 + 4096)          // [8grp][32sl][8b][8r] f32 = 64 KB
#define WS_H2    (WS_H1 + 65536)         // same
#define WS_KV    (WS_H2 + 65536)         // [8grp][6st][32sl][8b][4] f32 = 192 KB

typedef unsigned long long u64;

__device__ const float ATAB[6][5] = {
  {0.f, 0.f, 0.f, 0.f, 0.f},
  {0.161f, 0.f, 0.f, 0.f, 0.f},
  {-0.008480655492356989f, 0.335480655492357f, 0.f, 0.f, 0.f},
  {2.8971530571054935f, -6.359448489975075f, 4.3622954328695815f, 0.f, 0.f},
  {5.325864828439257f, -11.748883564062828f, 7.4955393428898365f, -0.09249506636175525f, 0.f},
  {5.86145544294642f, -12.92096931784711f, 8.159367898576159f, -0.071584973281401f, -0.028269050394068383f}
};
__device__ const float CNODE[6] = {0.f, 0.161f, 0.327f, 0.9f, 0.9800255409045097f, 1.f};
__device__ const float BTAB[6]  = {0.09646076681806523f, 0.01f, 0.4798896504144996f,
                                   1.379008574103742f, -3.290069515436081f, 2.324710524099774f};

__device__ __forceinline__ float softplusf_(float x) {
  return fmaxf(x, 0.0f) + log1pf(expf(-fabsf(x)));
}
__device__ __forceinline__ float dot4(float4 a, float4 b) {
  return (a.x*b.x + a.y*b.y) + (a.z*b.z + a.w*b.w);
}

// acquire: make same-XCD L2 data freshly visible (compiler-emitted buffer_inv;
// R2-proven mechanism). Locally-dirty L2 lines (our exchange data) survive.
__device__ __forceinline__ void acquire_fence() {
  __builtin_amdgcn_fence(__ATOMIC_ACQUIRE, "agent");
}

// ---- barrier: per-block slots + ballot poll, agent scope (R4-proven) ----
#define SLOT_STRIDE 16     // 16 u32 = 64B per slot
__device__ __forceinline__ void bar_arrive(unsigned* slots, int myslot, unsigned seq) {
  asm volatile("s_waitcnt vmcnt(0)" ::: "memory");   // plain data stores at L2 (write-through L1)
  __syncthreads();                                   // all waves drained
  if (threadIdx.x == 0) {
    __hip_atomic_store(&slots[myslot * SLOT_STRIDE], seq,
                       __ATOMIC_RELAXED, __HIP_MEMORY_SCOPE_AGENT);
  }
}
// wave-collective; guard bounds the spin (~100ms) so a bad mapping can't hang
__device__ __forceinline__ void bar_wait(unsigned* slots, unsigned seq) {
  const int sl = threadIdx.x & 31;
  int guard = 0;
  for (;;) {
    const unsigned v = __hip_atomic_load(&slots[sl * SLOT_STRIDE],
                                         __ATOMIC_RELAXED, __HIP_MEMORY_SCOPE_AGENT);
    if (__all(v >= seq)) break;
    if (++guard > (1 << 22)) break;    // diagnostic escape, never a 600s timeout
    __builtin_amdgcn_s_sleep(1);
  }
}
__device__ __forceinline__ void group_barrier(unsigned* slots, int myslot, unsigned seq) {
  bar_arrive(slots, myslot, seq);
  if (threadIdx.x < 64) bar_wait(slots, seq);
  __syncthreads();
}

__global__ void ws_init(unsigned* bar, u64* rankctr) {
  const int n = NGRP * NSL * SLOT_STRIDE;   // 4096
  for (int i = threadIdx.x; i < n; i += blockDim.x)
    __hip_atomic_store(&bar[i], 0u, __ATOMIC_RELAXED, __HIP_MEMORY_SCOPE_AGENT);
  if (threadIdx.x < NGRP)
    __hip_atomic_store(&rankctr[threadIdx.x], 0ull, __ATOMIC_RELAXED, __HIP_MEMORY_SCOPE_AGENT);
}

__global__ __launch_bounds__(BS) void ncde_fwd(
    const float* __restrict__ ts,
    const float* __restrict__ cd, const float* __restrict__ cc,
    const float* __restrict__ cb, const float* __restrict__ ca,
    const float* __restrict__ iw0, const float* __restrict__ ib0,
    const float* __restrict__ iw1, const float* __restrict__ ib1,
    const float* __restrict__ iw2, const float* __restrict__ ib2,
    const float* __restrict__ fw0, const float* __restrict__ fb0,
    const float* __restrict__ fw1, const float* __restrict__ fb1,
    const float* __restrict__ fw2, const float* __restrict__ fb2,
    const float* __restrict__ lw,  const float* __restrict__ lb,
    unsigned* __restrict__ bar, u64* __restrict__ rankctr,
    float* __restrict__ h1c, float* __restrict__ h2c,
    float* __restrict__ kvc, float* __restrict__ out)
{
  const int t = threadIdx.x;

  // ---- real XCD grouping: group == my XCC, slice == rank within it ----
  __shared__ unsigned s_g, s_s;
  if (t == 0) {
    unsigned xcc;
    asm volatile("s_getreg_b32 %0, hwreg(HW_REG_XCC_ID, 0, 32)" : "=s"(xcc));
    xcc &= 7;
    u64 r = __hip_atomic_fetch_add(&rankctr[xcc], 1ull,
                                   __ATOMIC_RELAXED, __HIP_MEMORY_SCOPE_AGENT);
    s_g = xcc;
    s_s = (unsigned)r & 31;
  }
  __syncthreads();
  const int g   = s_g;                    // all 32 group members share this XCD's L2
  const int s   = s_s;
  const int gr0 = g * GB;
  unsigned* slots = bar + g * NSL * SLOT_STRIDE;
  unsigned  bseq  = 0;
  float* h1cg = h1c + g * (NSL*GB*L1R);   // [32][8][8]  -> L2-resident
  float* h2cg = h2c + g * (NSL*GB*L2R);
  float* kvcg = kvc + g * (6*NSL*GB*4);   // [6][32][8][4]

  __shared__ float fw0s[L1R][P128];
  __shared__ float fw1s[L2R][P256];
  __shared__ float fw2s[L3R][P256];
  __shared__ float h1s[GB][P256];
  __shared__ float h2s[GB][P256];
  __shared__ float ysv[GB][P128];
  __shared__ float yloc[GB][NH];
  __shared__ float dxs[GB][NC];
  __shared__ float x0s[GB][NC];
  __shared__ float fb0s[L1R], fb1s[L2R], fb2s[L3R];
  __shared__ float tss[NSEQ];
  __shared__ float lgs[GB][NOUT], lses[GB];

  // ---- one-time: this slice's weights -> LDS ----
  {
    if (t < 256) {                       // fw0: 8 rows x 32 f4
      int row = t >> 5, j = t & 31;
      *(float4*)&fw0s[row][4*j] = *(const float4*)&fw0[(size_t)(s*L1R + row)*NH + 4*j];
    }
    {                                    // fw1: 8 rows x 64 f4 -> 1 f4/thread
      int r2 = t >> 6, j2 = t & 63;
      *(float4*)&fw1s[r2][4*j2] = *(const float4*)&fw1[(size_t)(s*L2R + r2)*NW + 4*j2];
    }
    #pragma unroll
    for (int i = 0; i < 8; ++i) {        // fw2: 64 rows x 64 f4 -> 8 f4/thread
      int e = t + BS*i; int r2 = e >> 6, j2 = e & 63;
      *(float4*)&fw2s[r2][4*j2] = *(const float4*)&fw2[(size_t)(s*L3R + r2)*NW + 4*j2];
    }
    if (t < L1R) fb0s[t] = fb0[s*L1R + t];
    if (t < L2R) fb1s[t] = fb1[s*L2R + t];
    if (t < L3R) fb2s[t] = fb2[s*L3R + t];
    if (t < NSEQ) tss[t] = ts[t];
  }

  // ---- init MLP (redundant per block, fully local) ----
  if (t < GB*NC) { int r = t >> 4, c = t & 15; x0s[r][c] = ca[((size_t)(gr0 + r)*NI)*NC + c]; }
  __syncthreads();
  #pragma unroll
  for (int i = 0; i < 4; ++i) {          // h1i: 2048 outs
    int e = t + BS*i; int r = e >> 8, row = e & 255;
    float a = ib0[row];
    #pragma unroll
    for (int k = 0; k < NC; ++k) a += iw0[row*NC + k] * x0s[r][k];
    h1s[r][row] = fmaxf(a, 0.f);
  }
  __syncthreads();
  #pragma unroll
  for (int i = 0; i < 4; ++i) {          // h2i
    int e = t + BS*i; int r = e >> 8, row = e & 255;
    float a = ib1[row];
    const float4* wr = (const float4*)&iw1[(size_t)row*NW];
    for (int k = 0; k < 64; ++k) a += dot4(wr[k], *(const float4*)&h1s[r][4*k]);
    h2s[r][row] = fmaxf(a, 0.f);
  }
  __syncthreads();
  #pragma unroll
  for (int i = 0; i < 2; ++i) {          // y0: 1024 outs
    int e = t + BS*i; int r = e >> 7, row = e & 127;
    float a = ib2[row];
    const float4* wr = (const float4*)&iw2[(size_t)row*NW];
    for (int k = 0; k < 64; ++k) a += dot4(wr[k], *(const float4*)&h2s[r][4*k]);
    yloc[r][row] = a;
  }
  __syncthreads();

  // ---- thread mappings ----
  const int lane = t & 63;
  const int w    = t >> 6;                      // wave index == batch row for L1/L2/L3
  const int yr   = t >> 5, yc4 = 4*(t & 31);    // t<256: one y-f4 (batch yr, cols yc4..+3)
  const int o    = t >> 3, q8 = t & 7;          // L1/L2: 8 threads per output
  const int orow = o & 7, obat = o >> 3;        // obat == w
  const int l3row = t & 63, l3c = t & 15, l3b = t >> 6;

  // ---- y and k stages live in registers (t<256) ----
  float4 yreg, kreg[6];
  if (t < 256) yreg = *(const float4*)&yloc[yr][yc4];

  // ---- 62 Tsit5 substeps ----
  for (int ss = 0; ss < NSUB; ++ss) {
    const int iv = ss >> 1, jv = ss & 1;
    const float h = (tss[iv+1] - tss[iv]) * 0.5f;
    const float t0f = (float)jv * h;

    float cdv = 0.f, ccv = 0.f, cbv = 0.f;
    if (t >= 256 && t < 256 + GB*NC) {
      const int tc = t - 256;
      const size_t base = ((size_t)(gr0 + (tc >> 4))*NI + iv)*NC + (tc & 15);
      cdv = cd[base]; ccv = cc[base]; cbv = cb[base];
    }

    for (int st = 0; st < 6; ++st) {
      // ---- phase A: stage state from registers + dX/dt ----
      if (t < 256) {
        float4 v = yreg;
        for (int jj = 0; jj < st; ++jj) {
          const float a = h * ATAB[st][jj];
          v.x += a*kreg[jj].x; v.y += a*kreg[jj].y;
          v.z += a*kreg[jj].z; v.w += a*kreg[jj].w;
        }
        *(float4*)&ysv[yr][yc4] = v;
      } else if (t < 256 + GB*NC) {
        const int tc = t - 256;
        const float f = t0f + CNODE[st] * h;
        dxs[tc >> 4][tc & 15] = (3.f*cdv*f + 2.f*ccv)*f + cbv;
      }
      __syncthreads();

      // ---- L1: h1 slice -> plain packed store (L2-resident, [slice][batch][row]) ----
      {
        float a0 = 0.f, a1 = 0.f;
        #pragma unroll
        for (int i = 0; i < 4; i += 2) {
          a0 += dot4(*(const float4*)&fw0s[orow][4*(q8+8*i)],     *(const float4*)&ysv[obat][4*(q8+8*i)]);
          a1 += dot4(*(const float4*)&fw0s[orow][4*(q8+8*(i+1))], *(const float4*)&ysv[obat][4*(q8+8*(i+1))]);
        }
        float a = a0 + a1;
        a += __shfl_xor(a, 1); a += __shfl_xor(a, 2); a += __shfl_xor(a, 4);
        const float praw = __shfl(a, (lane & 7) * 8);   // lane L -> row (L&7) of batch w
        if (lane < 8)
          h1cg[(s*GB + w)*L1R + lane] = softplusf_(fb0s[lane] + praw);
      }
      group_barrier(slots, s, ++bseq);
      acquire_fence();

      // consume full h1: one cached x4 load/thread (local L2), scatter to LDS
      {
        const float4 v = *(const float4*)(h1cg + 4*t);
        *(float4*)&h1s[(t >> 1) & 7][(t >> 4)*8 + 4*(t & 1)] = v;
      }
      __syncthreads();

      // ---- L2: h2 slice -> plain packed store ----
      {
        float a0 = 0.f, a1 = 0.f;
        #pragma unroll
        for (int i = 0; i < 8; i += 2) {
          a0 += dot4(*(const float4*)&fw1s[orow][4*(q8+8*i)],     *(const float4*)&h1s[obat][4*(q8+8*i)]);
          a1 += dot4(*(const float4*)&fw1s[orow][4*(q8+8*(i+1))], *(const float4*)&h1s[obat][4*(q8+8*(i+1))]);
        }
        float a = a0 + a1;
        a += __shfl_xor(a, 1); a += __shfl_xor(a, 2); a += __shfl_xor(a, 4);
        const float praw = __shfl(a, (lane & 7) * 8);
        if (lane < 8)
          h2cg[(s*GB + w)*L2R + lane] = softplusf_(fb1s[lane] + praw);
      }
      group_barrier(slots, s, ++bseq);
      acquire_fence();

      // consume full h2
      {
        const float4 v = *(const float4*)(h2cg + 4*t);
        *(float4*)&h2s[(t >> 1) & 7][(t >> 4)*8 + 4*(t & 1)] = v;
      }
      __syncthreads();

      // ---- L3: one fw2 row per thread -> one x4 plain store per wave ----
      {
        const float4* wr = (const float4*)&fw2s[l3row][0];
        const float4* xr = (const float4*)&h2s[l3b][0];
        float a0 = 0.f, a1 = 0.f, a2 = 0.f, a3 = 0.f;
        #pragma unroll 4
        for (int i = 0; i < 64; i += 4) {
          a0 += dot4(wr[i+0], xr[i+0]);
          a1 += dot4(wr[i+1], xr[i+1]);
          a2 += dot4(wr[i+2], xr[i+2]);
          a3 += dot4(wr[i+3], xr[i+3]);
        }
        float v0 = tanhf(((a0+a1)+(a2+a3)) + fb2s[l3row]) * dxs[l3b][l3c];
        v0 += __shfl_xor(v0, 1);
        v0 += __shfl_xor(v0, 2);
        v0 += __shfl_xor(v0, 4);
        v0 += __shfl_xor(v0, 8);
        float4 pk;
        pk.x = __shfl(v0, 0);  pk.y = __shfl(v0, 16);
        pk.z = __shfl(v0, 32); pk.w = __shfl(v0, 48);
        if (lane == 0)
          *(float4*)&kvcg[((st*NSL + s)*GB + w)*4] = pk;
      }
      // kv: arrive, then only consumer waves (t<256) poll; waves 4-7 run ahead
      bar_arrive(slots, s, ++bseq);
      if (t < 256) {
        bar_wait(slots, bseq);
        acquire_fence();
        kreg[st] = *(const float4*)(kvcg + ((st*NSL + (t & 31))*GB + yr)*4);
      }
    }

    // ---- y update in registers ----
    if (t < 256) {
      #pragma unroll
      for (int s2 = 0; s2 < 6; ++s2) {
        const float a = h * BTAB[s2];
        yreg.x += a*kreg[s2].x; yreg.y += a*kreg[s2].y;
        yreg.z += a*kreg[s2].z; yreg.w += a*kreg[s2].w;
      }
    }
  }

  // ---- write y back for readout ----
  if (t < 256) *(float4*)&yloc[yr][yc4] = yreg;
  __syncthreads();

  // ---- readout by rank 0 of each group ----
  if (s == 0) {
    if (t < GB*NOUT) {
      const int r = t / NOUT, oo = t % NOUT;
      float a = lb[oo];
      const float4* wr = (const float4*)&lw[(size_t)oo*NH];
      #pragma unroll
      for (int k = 0; k < 32; ++k) a += dot4(wr[k], *(const float4*)&yloc[r][4*k]);
      lgs[r][oo] = a;
    }
    __syncthreads();
    if (t < GB) {
      float m = lgs[t][0];
      for (int oo = 1; oo < NOUT; ++oo) m = fmaxf(m, lgs[t][oo]);
      float se = 0.f;
      for (int oo = 0; oo < NOUT; ++oo) se += expf(lgs[t][oo] - m);
      lses[t] = m + logf(se);
    }
    __syncthreads();
    if (t < GB*NOUT) {
      const int r = t / NOUT, oo = t % NOUT;
      out[(gr0 + r)*NOUT + oo] = lgs[r][oo] - lses[r];
    }
  }
}

extern "C" void kernel_launch(void* const* d_in, const int* in_sizes, int n_in,
                              void* d_out, int out_size, void* d_ws, size_t ws_size,
                              hipStream_t stream) {
  const float* ts  = (const float*)d_in[0];
  const float* cd  = (const float*)d_in[1];
  const float* cc  = (const float*)d_in[2];
  const float* cb  = (const float*)d_in[3];
  const float* ca  = (const float*)d_in[4];
  const float* iw0 = (const float*)d_in[5];
  const float* ib0 = (const float*)d_in[6];
  const float* iw1 = (const float*)d_in[7];
  const float* ib1 = (const float*)d_in[8];
  const float* iw2 = (const float*)d_in[9];
  const float* ib2 = (const float*)d_in[10];
  const float* fw0 = (const float*)d_in[11];
  const float* fb0 = (const float*)d_in[12];
  const float* fw1 = (const float*)d_in[13];
  const float* fb1 = (const float*)d_in[14];
  const float* fw2 = (const float*)d_in[15];
  const float* fb2 = (const float*)d_in[16];
  const float* lw  = (const float*)d_in[17];
  const float* lb  = (const float*)d_in[18];

  char* ws = (char*)d_ws;
  unsigned* bar  = (unsigned*)(ws + WS_BAR);
  u64*      rctr = (u64*)(ws + WS_CTRL);
  float*    h1c  = (float*)(ws + WS_H1);
  float*    h2c  = (float*)(ws + WS_H2);
  float*    kvc  = (float*)(ws + WS_KV);

  ws_init<<<1, 512, 0, stream>>>(bar, rctr);
  ncde_fwd<<<NBLK, BS, 0, stream>>>(ts, cd, cc, cb, ca, iw0, ib0, iw1, ib1, iw2, ib2,
                                    fw0, fb0, fw1, fb1, fw2, fb2, lw, lb,
                                    bar, rctr, h1c, h2c, kvc, (float*)d_out);
}

// Round 12
// 5463.477 us; speedup vs baseline: 3.0976x; 3.0976x over previous
//
#include <hip/hip_runtime.h>

#define NBATCH 64
#define NSEQ   32
#define NI     31
#define NC     16
#define NH     128
#define NW     256
#define NOUT   10
#define NSUB   62          // 31 intervals * 2 substeps

#define NGRP 8             // batch groups
#define GB   8             // batch rows per group
#define HB   4             // rows per half
#define NSL  32            // slice blocks per group
#define NBLK (NGRP*NSL)    // 256 blocks = 1 per CU (LDS-forced)
#define BS   512

// per-slice weight ownership
#define L1R 8              // fw0 rows  (256/32)
#define L2R 8              // fw1 rows  (256/32)
#define L3H 4              // h-dims of fw2 (128/32)
#define L3R 64             // fw2 rows = L3H*16

// padded LDS strides (floats)
#define P128 132
#define P256 260

// workspace layout (bytes)
#define WS_BAR   0                       // 8 groups * 2 streams * 32 slots * 64B = 32 KB
#define WS_H1    32768                   // [8grp][8b][32sl][8r] f32 = 64 KB
#define WS_H2    (32768 + 65536)
#define WS_KV    (32768 + 131072)        // [8grp][6st][8b][32sl][4] f32 = 192 KB

typedef float f4v __attribute__((ext_vector_type(4)));

__device__ const float ATAB[6][5] = {
  {0.f, 0.f, 0.f, 0.f, 0.f},
  {0.161f, 0.f, 0.f, 0.f, 0.f},
  {-0.008480655492356989f, 0.335480655492357f, 0.f, 0.f, 0.f},
  {2.8971530571054935f, -6.359448489975075f, 4.3622954328695815f, 0.f, 0.f},
  {5.325864828439257f, -11.748883564062828f, 7.4955393428898365f, -0.09249506636175525f, 0.f},
  {5.86145544294642f, -12.92096931784711f, 8.159367898576159f, -0.071584973281401f, -0.028269050394068383f}
};
__device__ const float CNODE[6] = {0.f, 0.161f, 0.327f, 0.9f, 0.9800255409045097f, 1.f};
__device__ const float BTAB[6]  = {0.09646076681806523f, 0.01f, 0.4798896504144996f,
                                   1.379008574103742f, -3.290069515436081f, 2.324710524099774f};

__device__ __forceinline__ float softplusf_(float x) {
  return fmaxf(x, 0.0f) + log1pf(expf(-fabsf(x)));
}
__device__ __forceinline__ float dot4(float4 a, float4 b) {
  return (a.x*b.x + a.y*b.y) + (a.z*b.z + a.w*b.w);
}

// ---- device-coherent transport (agent scope; R4/R8-proven) ----
__device__ __forceinline__ void sta_f32(float* p, float v) {
  __hip_atomic_store(p, v, __ATOMIC_RELAXED, __HIP_MEMORY_SCOPE_AGENT);
}
__device__ __forceinline__ f4v lda_f32x4(const float* p) {
  f4v r;
  asm volatile("global_load_dwordx4 %0, %1, off sc0 sc1\n\ts_waitcnt vmcnt(0)"
               : "=v"(r) : "v"(p) : "memory");
  return r;
}

// ---- barrier primitives (R4-proven), split arrive/wait for pipelining ----
#define SLOT_STRIDE 16     // 64B per slot
__device__ __forceinline__ void bar_arrive(unsigned* slots, int myslot, unsigned seq) {
  asm volatile("s_waitcnt vmcnt(0)" ::: "memory");   // data stores acked at coherence point
  __syncthreads();                                   // all waves drained
  if (threadIdx.x == 0) {
    __hip_atomic_store(&slots[myslot * SLOT_STRIDE], seq,
                       __ATOMIC_RELAXED, __HIP_MEMORY_SCOPE_AGENT);
  }
}
__device__ __forceinline__ void bar_wait(unsigned* slots, unsigned seq) {
  if (threadIdx.x < 64) {
    const int sl = threadIdx.x & 31;
    int guard = 0;
    for (;;) {
      const unsigned v = __hip_atomic_load(&slots[sl * SLOT_STRIDE],
                                           __ATOMIC_RELAXED, __HIP_MEMORY_SCOPE_AGENT);
      if (__all(v >= seq)) break;
      if (++guard > (1 << 22)) break;    // diagnostic escape, never a 600s timeout
      __builtin_amdgcn_s_sleep(1);
    }
  }
}

__global__ void bar_init(unsigned* bar) {
  const int n = NGRP * 2 * NSL * SLOT_STRIDE;   // 8192
  for (int i = threadIdx.x; i < n; i += blockDim.x)
    __hip_atomic_store(&bar[i], 0u, __ATOMIC_RELAXED, __HIP_MEMORY_SCOPE_AGENT);
}

__global__ __launch_bounds__(BS) void ncde_fwd(
    const float* __restrict__ ts,
    const float* __restrict__ cd, const float* __restrict__ cc,
    const float* __restrict__ cb, const float* __restrict__ ca,
    const float* __restrict__ iw0, const float* __restrict__ ib0,
    const float* __restrict__ iw1, const float* __restrict__ ib1,
    const float* __restrict__ iw2, const float* __restrict__ ib2,
    const float* __restrict__ fw0, const float* __restrict__ fb0,
    const float* __restrict__ fw1, const float* __restrict__ fb1,
    const float* __restrict__ fw2, const float* __restrict__ fb2,
    const float* __restrict__ lw,  const float* __restrict__ lb,
    unsigned* __restrict__ bar, float* __restrict__ h1c, float* __restrict__ h2c,
    float* __restrict__ kvc, float* __restrict__ out)
{
  const int t   = threadIdx.x;
  const int g   = blockIdx.x & 7;         // group (XCD heuristic; correctness-independent)
  const int s   = blockIdx.x >> 3;        // slice 0..31
  const int gr0 = g * GB;
  unsigned* slotsA = bar + (g*2    ) * NSL * SLOT_STRIDE;
  unsigned* slotsB = bar + (g*2 + 1) * NSL * SLOT_STRIDE;
  unsigned  seqA = 0, seqB = 0;
  float* h1cg = h1c + g * (GB*NSL*L1R);   // [8b][32s][8r]
  float* h2cg = h2c + g * (GB*NSL*L2R);
  float* kvcg = kvc + g * (6*GB*NSL*4);   // [6st][8b][32s][4h]

  __shared__ float fw0s[L1R][P128];
  __shared__ float fw1s[L2R][P256];
  __shared__ float fw2s[L3R][P256];
  __shared__ float h1s[GB][P256];
  __shared__ float h2s[GB][P256];
  __shared__ float ysv[GB][P128];
  __shared__ float yloc[GB][NH];
  __shared__ float kvs[6][GB][NH];
  __shared__ float dxs[GB][NC];
  __shared__ float x0s[GB][NC];
  __shared__ float kpart[256];
  __shared__ float fb0s[L1R], fb1s[L2R], fb2s[L3R];
  __shared__ float tss[NSEQ];
  __shared__ float lgs[GB][NOUT], lses[GB];

  // ---- one-time: this slice's weights -> LDS ----
  {
    if (t < 256) {                       // fw0: 8 rows x 32 f4
      int row = t >> 5, j = t & 31;
      *(float4*)&fw0s[row][4*j] = *(const float4*)&fw0[(size_t)(s*L1R + row)*NH + 4*j];
    }
    {                                    // fw1: 8 rows x 64 f4
      int r2 = t >> 6, j2 = t & 63;
      *(float4*)&fw1s[r2][4*j2] = *(const float4*)&fw1[(size_t)(s*L2R + r2)*NW + 4*j2];
    }
    #pragma unroll
    for (int i = 0; i < 8; ++i) {        // fw2: 64 rows x 64 f4
      int e = t + BS*i; int r2 = e >> 6, j2 = e & 63;
      *(float4*)&fw2s[r2][4*j2] = *(const float4*)&fw2[(size_t)(s*L3R + r2)*NW + 4*j2];
    }
    if (t < L1R) fb0s[t] = fb0[s*L1R + t];
    if (t < L2R) fb1s[t] = fb1[s*L2R + t];
    if (t < L3R) fb2s[t] = fb2[s*L3R + t];
    if (t < NSEQ) tss[t] = ts[t];
  }

  // ---- init MLP (redundant per block, fully local) ----
  if (t < GB*NC) { int r = t >> 4, c = t & 15; x0s[r][c] = ca[((size_t)(gr0 + r)*NI)*NC + c]; }
  __syncthreads();
  #pragma unroll
  for (int i = 0; i < 4; ++i) {          // h1i
    int e = t + BS*i; int r = e >> 8, row = e & 255;
    float a = ib0[row];
    #pragma unroll
    for (int k = 0; k < NC; ++k) a += iw0[row*NC + k] * x0s[r][k];
    h1s[r][row] = fmaxf(a, 0.f);
  }
  __syncthreads();
  #pragma unroll
  for (int i = 0; i < 4; ++i) {          // h2i
    int e = t + BS*i; int r = e >> 8, row = e & 255;
    float a = ib1[row];
    const float4* wr = (const float4*)&iw1[(size_t)row*NW];
    for (int k = 0; k < 64; ++k) a += dot4(wr[k], *(const float4*)&h1s[r][4*k]);
    h2s[r][row] = fmaxf(a, 0.f);
  }
  __syncthreads();
  #pragma unroll
  for (int i = 0; i < 2; ++i) {          // y0
    int e = t + BS*i; int r = e >> 7, row = e & 127;
    float a = ib2[row];
    const float4* wr = (const float4*)&iw2[(size_t)row*NW];
    for (int k = 0; k < 64; ++k) a += dot4(wr[k], *(const float4*)&h2s[r][4*k]);
    yloc[r][row] = a;
  }
  __syncthreads();

  // ---- 62 Tsit5 substeps, two-half pipeline ----
  for (int ss = 0; ss < NSUB; ++ss) {
    const int iv = ss >> 1, jv = ss & 1;
    const float h = (tss[iv+1] - tss[iv]) * 0.5f;
    const float t0f = (float)jv * h;

    // coeff holders: t<128 -> (half = t>>6, b4 = (t&63)>>4, c = t&15)
    float cdv = 0.f, ccv = 0.f, cbv = 0.f;
    if (t < 128) {
      const int tc = t & 63;
      const size_t base = ((size_t)(gr0 + (t >> 6)*HB + (tc >> 4))*NI + iv)*NC + (tc & 15);
      cdv = cd[base]; ccv = cc[base]; cbv = cb[base];
    }

    for (int st = 0; st < 6; ++st) {

      // ---------- phase 1 (ys + dxs + L1) per half ----------
      #define PHASE1(hb)                                                          \
      {                                                                           \
        { /* ys: 512 vals (4b x 128) */                                           \
          const int b = (hb)*HB + (t >> 7), c = t & 127;                          \
          float v = yloc[b][c];                                                   \
          for (int jj = 0; jj < st; ++jj) v += h * ATAB[st][jj] * kvs[jj][b][c];  \
          ysv[b][c] = v;                                                          \
        }                                                                         \
        if ((t >> 6) == (hb) && t < 128) {                                        \
          const int tc = t & 63;                                                  \
          const float f = t0f + CNODE[st] * h;                                    \
          dxs[(hb)*HB + (tc >> 4)][tc & 15] = (3.f*cdv*f + 2.f*ccv)*f + cbv;      \
        }                                                                         \
        __syncthreads();                                                          \
        { /* L1: 32 outs x 16 thr */                                              \
          const int outI = t >> 4, q16 = t & 15;                                  \
          const int orow = outI & 7, b = (hb)*HB + (outI >> 3);                   \
          float a = dot4(*(const float4*)&fw0s[orow][4*q16],                      \
                         *(const float4*)&ysv[b][4*q16])                          \
                  + dot4(*(const float4*)&fw0s[orow][4*(q16+16)],                 \
                         *(const float4*)&ysv[b][4*(q16+16)]);                    \
          a += __shfl_xor(a,1); a += __shfl_xor(a,2);                             \
          a += __shfl_xor(a,4); a += __shfl_xor(a,8);                             \
          if (q16 == 0)                                                           \
            sta_f32(&h1cg[(b*NSL + s)*L1R + orow], softplusf_(fb0s[orow] + a));   \
        }                                                                         \
      }

      // ---------- phase 2 (L2) per half ----------
      #define PHASE2(hb)                                                          \
      {                                                                           \
        const int outI = t >> 4, q16 = t & 15;                                    \
        const int orow = outI & 7, b = (hb)*HB + (outI >> 3);                     \
        float a = 0.f;                                                            \
        _Pragma("unroll")                                                         \
        for (int i = 0; i < 4; ++i) {                                             \
          const int j = q16 + 16*i;                                               \
          a += dot4(*(const float4*)&fw1s[orow][4*j],                             \
                    *(const float4*)&h1s[b][4*j]);                                \
        }                                                                         \
        a += __shfl_xor(a,1); a += __shfl_xor(a,2);                               \
        a += __shfl_xor(a,4); a += __shfl_xor(a,8);                               \
        if (q16 == 0)                                                             \
          sta_f32(&h2cg[(b*NSL + s)*L2R + orow], softplusf_(fb1s[orow] + a));     \
      }

      // ---------- phase 3 (L3 + kv) per half ----------
      #define PHASE3(hb)                                                          \
      {                                                                           \
        const int pair = t >> 1, kh = t & 1;                                      \
        const int row = pair & 63, b = (hb)*HB + (pair >> 6);                     \
        const float4* wr = (const float4*)&fw2s[row][0];                          \
        const float4* xr = (const float4*)&h2s[b][0];                             \
        float a0 = 0.f, a1 = 0.f;                                                 \
        _Pragma("unroll 4")                                                       \
        for (int i = kh*32; i < kh*32 + 32; i += 2) {                             \
          a0 += dot4(wr[i],   xr[i]);                                             \
          a1 += dot4(wr[i+1], xr[i+1]);                                           \
        }                                                                         \
        float acc = a0 + a1;                                                      \
        acc += __shfl_xor(acc, 1);                                                \
        if (kh == 0)                                                              \
          kpart[pair] = tanhf(acc + fb2s[row]) * dxs[b][row & 15];                \
        __syncthreads();                                                          \
        if (t < 16) {                                                             \
          const int b4 = t >> 2, hh = t & 3;                                      \
          const float* kp = &kpart[b4*64 + hh*16];                                \
          float s2 = 0.f;                                                         \
          _Pragma("unroll")                                                       \
          for (int c = 0; c < 16; ++c) s2 += kp[c];                               \
          sta_f32(&kvcg[((st*GB + (hb)*HB + b4)*NSL + s)*4 + hh], s2);            \
        }                                                                         \
      }

      PHASE1(0); bar_arrive(slotsA, s, ++seqA);
      PHASE1(1); bar_arrive(slotsB, s, ++seqB);

      bar_wait(slotsA, seqA); __syncthreads();
      if (t < 256) {                       // read h1 half A (contiguous 4KB)
        const f4v v = lda_f32x4(h1cg + 4*t);
        *(f4v*)&h1s[t >> 6][4*t & 255] = v;
      }
      __syncthreads();
      PHASE2(0); bar_arrive(slotsA, s, ++seqA);

      bar_wait(slotsB, seqB); __syncthreads();
      if (t < 256) {                       // read h1 half B
        const f4v v = lda_f32x4(h1cg + 1024 + 4*t);
        *(f4v*)&h1s[HB + (t >> 6)][4*t & 255] = v;
      }
      __syncthreads();
      PHASE2(1); bar_arrive(slotsB, s, ++seqB);

      bar_wait(slotsA, seqA); __syncthreads();
      if (t < 256) {                       // read h2 half A
        const f4v v = lda_f32x4(h2cg + 4*t);
        *(f4v*)&h2s[t >> 6][4*t & 255] = v;
      }
      __syncthreads();
      PHASE3(0); bar_arrive(slotsA, s, ++seqA);

      bar_wait(slotsB, seqB); __syncthreads();
      if (t < 256) {                       // read h2 half B
        const f4v v = lda_f32x4(h2cg + 1024 + 4*t);
        *(f4v*)&h2s[HB + (t >> 6)][4*t & 255] = v;
      }
      __syncthreads();
      PHASE3(1); bar_arrive(slotsB, s, ++seqB);

      bar_wait(slotsA, seqA); __syncthreads();
      if (t < 128) {                       // kv half A -> LDS
        const int b = t >> 5, sl = t & 31;
        const f4v v = lda_f32x4(kvcg + ((st*GB + b)*NSL + sl)*4);
        *(f4v*)&kvs[st][b][4*sl] = v;
      }
      bar_wait(slotsB, seqB); __syncthreads();
      if (t < 128) {                       // kv half B -> LDS
        const int b = HB + (t >> 5), sl = t & 31;
        const f4v v = lda_f32x4(kvcg + ((st*GB + b)*NSL + sl)*4);
        *(f4v*)&kvs[st][b][4*sl] = v;
      }
      __syncthreads();

      #undef PHASE1
      #undef PHASE2
      #undef PHASE3
    }

    // ---- y update (1024 vals, 2 per thread) ----
    #pragma unroll
    for (int i = 0; i < 2; ++i) {
      const int e = t + BS*i, b = e >> 7, c = e & 127;
      float v = yloc[b][c];
      #pragma unroll
      for (int j = 0; j < 6; ++j) v += h * BTAB[j] * kvs[j][b][c];
      yloc[b][c] = v;
    }
    __syncthreads();
  }

  // ---- readout by slice 0 of each group ----
  if (s == 0) {
    if (t < GB*NOUT) {
      const int r = t / NOUT, oo = t % NOUT;
      float a = lb[oo];
      const float4* wr = (const float4*)&lw[(size_t)oo*NH];
      #pragma unroll
      for (int k = 0; k < 32; ++k) a += dot4(wr[k], *(const float4*)&yloc[r][4*k]);
      lgs[r][oo] = a;
    }
    __syncthreads();
    if (t < GB) {
      float m = lgs[t][0];
      for (int oo = 1; oo < NOUT; ++oo) m = fmaxf(m, lgs[t][oo]);
      float se = 0.f;
      for (int oo = 0; oo < NOUT; ++oo) se += expf(lgs[t][oo] - m);
      lses[t] = m + logf(se);
    }
    __syncthreads();
    if (t < GB*NOUT) {
      const int r = t / NOUT, oo = t % NOUT;
      out[(gr0 + r)*NOUT + oo] = lgs[r][oo] - lses[r];
    }
  }
}

extern "C" void kernel_launch(void* const* d_in, const int* in_sizes, int n_in,
                              void* d_out, int out_size, void* d_ws, size_t ws_size,
                              hipStream_t stream) {
  const float* ts  = (const float*)d_in[0];
  const float* cd  = (const float*)d_in[1];
  const float* cc  = (const float*)d_in[2];
  const float* cb  = (const float*)d_in[3];
  const float* ca  = (const float*)d_in[4];
  const float* iw0 = (const float*)d_in[5];
  const float* ib0 = (const float*)d_in[6];
  const float* iw1 = (const float*)d_in[7];
  const float* ib1 = (const float*)d_in[8];
  const float* iw2 = (const float*)d_in[9];
  const float* ib2 = (const float*)d_in[10];
  const float* fw0 = (const float*)d_in[11];
  const float* fb0 = (const float*)d_in[12];
  const float* fw1 = (const float*)d_in[13];
  const float* fb1 = (const float*)d_in[14];
  const float* fw2 = (const float*)d_in[15];
  const float* fb2 = (const float*)d_in[16];
  const float* lw  = (const float*)d_in[17];
  const float* lb  = (const float*)d_in[18];

  char* ws = (char*)d_ws;
  unsigned* bar = (unsigned*)(ws + WS_BAR);
  float* h1c = (float*)(ws + WS_H1);
  float* h2c = (float*)(ws + WS_H2);
  float* kvc = (float*)(ws + WS_KV);

  bar_init<<<1, 1024, 0, stream>>>(bar);
  ncde_fwd<<<NBLK, BS, 0, stream>>>(ts, cd, cc, cb, ca, iw0, ib0, iw1, ib1, iw2, ib2,
                                    fw0, fb0, fw1, fb1, fw2, fb2, lw, lb,
                                    bar, h1c, h2c, kvc, (float*)d_out);
}